// Round 19
// baseline (166.058 us; speedup 1.0000x reference)
//
#include <hip/hip_runtime.h>
#include <hip/hip_bf16.h>
#include <hip/hip_fp16.h>

#define N_NODES 100000
#define P_PATHS 10000
#define NBUK 391          // ceil(100000/256), bucket = dst>>8
#define FEAT_BLKS 782     // 128 nodes/block
#define HIST_BLKS 416     // 416*4096 >= E
#define WPREP_BLKS 94     // 94*4 = 376 wprep units
#define LOG2E 1.4426950408889634f
#define BC_CAP 5120       // bucketC LDS pair cache (20KB)

typedef __attribute__((ext_vector_type(8))) short s16x8;
typedef __attribute__((ext_vector_type(4))) short s16x4;
typedef __attribute__((ext_vector_type(4))) float f32x4;
typedef __attribute__((ext_vector_type(8))) _Float16 f16x8;
typedef __attribute__((ext_vector_type(2))) _Float16 f16x2;

__device__ __forceinline__ float h2f(short s) {
    return __half2float(__builtin_bit_cast(__half, s));
}
__device__ __forceinline__ short f2h(float v) {
    return __builtin_bit_cast(short, __float2half(v));
}

// ================= Fused: feat-MFMA(fp16) | bucket-hist | weight-prep ======
__global__ __launch_bounds__(256) void k_fused1(const float* __restrict__ x,
                                                const float* __restrict__ fc_w,
                                                const float* __restrict__ attn_l,
                                                const float* __restrict__ attn_r,
                                                __half* __restrict__ feat,
                                                float* __restrict__ el,
                                                float* __restrict__ er,
                                                const int* __restrict__ dst,
                                                int* __restrict__ buktot,
                                                const float* __restrict__ w1,
                                                const float* __restrict__ w2,
                                                const float* __restrict__ w3,
                                                const float* __restrict__ w4,
                                                const float* __restrict__ w5,
                                                const float* __restrict__ w6,
                                                short* __restrict__ wf, int E) {
    __shared__ float s_w[64 * 64];
    __shared__ float s_wx[64 * 16];
    __shared__ int hcnt[NBUK];
    int tid = threadIdx.x;
    int bb = blockIdx.x;

    if (bb < FEAT_BLKS) {
        // ---- feat = x@fc_w, fp16 MFMA (feat stored fp16 anyway), 128 nodes
        for (int i = tid; i < 4096; i += 256) s_w[i] = fc_w[i];
        __syncthreads();
        for (int i = tid; i < 1024; i += 256) {
            int k = i >> 4, c = i & 15;
            float v = 0.f;
            if (c < 8) {
                int h = c & 3;
                const float* av = (c < 4) ? attn_l : attn_r;
                for (int f = 0; f < 16; ++f) v += s_w[k * 64 + h * 16 + f] * av[h * 16 + f];
            }
            s_wx[i] = v * LOG2E;   // prescale -> k_agg uses raw v_exp_f32
        }
        __syncthreads();

        int w = tid >> 6, l = tid & 63;
        int c_lane = l & 15, kg = l >> 4;

        f16x8 wfr[5][2];
#pragma unroll
        for (int ct = 0; ct < 5; ++ct)
#pragma unroll
            for (int ks = 0; ks < 2; ++ks) {
                f16x8 h8;
#pragma unroll
                for (int i = 0; i < 8; ++i) {
                    int k = ks * 32 + kg * 8 + i;
                    float v = (ct < 4) ? s_w[k * 64 + ct * 16 + c_lane]
                                       : s_wx[k * 16 + c_lane];
                    h8[i] = (_Float16)v;
                }
                wfr[ct][ks] = h8;
            }

        int nbase = bb * 128 + w * 32;
#pragma unroll 1
        for (int mt = 0; mt < 2; ++mt) {
            int m0 = nbase + mt * 16;
            if (m0 >= N_NODES) break;
            int arow = m0 + c_lane;
            size_t axoff = (size_t)(arow < N_NODES ? arow : N_NODES - 1) * 64;
            f16x8 af[2];
#pragma unroll
            for (int ks = 0; ks < 2; ++ks) {
                const float* xp = x + axoff + ks * 32 + kg * 8;
                float4 v0 = *(const float4*)xp;
                float4 v1 = *(const float4*)(xp + 4);
                f16x8 h8;
                h8[0] = (_Float16)v0.x; h8[1] = (_Float16)v0.y;
                h8[2] = (_Float16)v0.z; h8[3] = (_Float16)v0.w;
                h8[4] = (_Float16)v1.x; h8[5] = (_Float16)v1.y;
                h8[6] = (_Float16)v1.z; h8[7] = (_Float16)v1.w;
                af[ks] = h8;
            }
            int r0 = m0 + kg * 4;
#pragma unroll
            for (int ct = 0; ct < 5; ++ct) {
                f32x4 acc = {0.f, 0.f, 0.f, 0.f};
#pragma unroll
                for (int ks = 0; ks < 2; ++ks)
                    acc = __builtin_amdgcn_mfma_f32_16x16x32_f16(af[ks], wfr[ct][ks], acc, 0, 0, 0);
                if (ct < 4) {
#pragma unroll
                    for (int j = 0; j < 4; ++j) {
                        int r = r0 + j;
                        if (r < N_NODES)
                            feat[(size_t)r * 64 + ct * 16 + c_lane] = __float2half(acc[j]);
                    }
                } else {
                    if (c_lane < 4) {
#pragma unroll
                        for (int j = 0; j < 4; ++j) {
                            int r = r0 + j;
                            if (r < N_NODES) el[r * 4 + c_lane] = acc[j];
                        }
                    } else if (c_lane < 8) {
#pragma unroll
                        for (int j = 0; j < 4; ++j) {
                            int r = r0 + j;
                            if (r < N_NODES) er[r * 4 + (c_lane - 4)] = acc[j];
                        }
                    }
                }
            }
        }
    } else if (bb < FEAT_BLKS + HIST_BLKS) {
        // ---------------- bucket histogram (LDS-staged) --------------------
        int hb = bb - FEAT_BLKS;
        for (int i = tid; i < NBUK; i += 256) hcnt[i] = 0;
        __syncthreads();
#pragma unroll
        for (int j = 0; j < 4; ++j) {
            int i = hb * 4096 + j * 1024 + tid * 4;
            if (i + 3 < E) {
                int4 d4 = *(const int4*)(dst + i);
                atomicAdd(&hcnt[d4.x >> 8], 1);
                atomicAdd(&hcnt[d4.y >> 8], 1);
                atomicAdd(&hcnt[d4.z >> 8], 1);
                atomicAdd(&hcnt[d4.w >> 8], 1);
            } else {
                for (int k = i; k < E && k < i + 4; ++k)
                    atomicAdd(&hcnt[dst[k] >> 8], 1);
            }
        }
        __syncthreads();
        for (int i = tid; i < NBUK; i += 256)
            if (hcnt[i]) atomicAdd(buktot + i, hcnt[i]);
    } else {
        // ---------------- weight prep: f32 -> fp16 B-fragments -------------
        const int nblk[6] = {240, 60, 40, 20, 12, 4};
        const int din_[6] = {640, 180, 150, 128, 80, 64};
        const int dout_[6] = {180, 150, 128, 80, 64, 32};
        const int ks_[6]  = {20, 6, 5, 4, 3, 2};
        const int off_[6] = {0, 122880, 153600, 174080, 184320, 190464};
        const float* wp[6] = {w1, w2, w3, w4, w5, w6};

        int b = (bb - FEAT_BLKS - HIST_BLKS) * 4 + (tid >> 6);
        int layer = 0;
        while (layer < 5 && b >= nblk[layer]) { b -= nblk[layer]; ++layer; }
        int KS = ks_[layer];
        int ct = b / KS, ks = b % KS;
        int l = tid & 63;
        int c = ct * 16 + (l & 15);
        int k0 = ks * 32 + ((l >> 4) * 8);
        int din = din_[layer], dout = dout_[layer];
        const float* w = wp[layer];
        s16x8 vh;
#pragma unroll
        for (int i = 0; i < 8; ++i) {
            int k = k0 + i;
            float v = (k < din && c < dout) ? w[k * dout + c] : 0.f;
            vh[i] = f2h(v);
        }
        size_t o = (size_t)off_[layer] + ((size_t)(ct * KS + ks) * 64 + l) * 8;
        *(s16x8*)(wf + o) = vh;
    }
}

// ---------------- bucketA v3: local scan of buktot, LDS-sorted writeout ----
// packed word: src (17 bits) | (dst & 255) << 17
// Each block re-computes the global bucket scan from buktot (cheap) and
// reserves via bukcnt2. Block 0 publishes bukstart + rowptr[N]=E.
__global__ __launch_bounds__(256) void k_bucketA(const int* __restrict__ src,
                                                 const int* __restrict__ dst,
                                                 const int* __restrict__ buktot,
                                                 int* __restrict__ bukcnt2,
                                                 int* __restrict__ bukstart,
                                                 int* __restrict__ rowptr,
                                                 unsigned* __restrict__ pair, int E) {
    __shared__ int cnt[NBUK];
    __shared__ int gexc[NBUK];
    __shared__ int seg[NBUK];
    __shared__ int gbase[NBUK];
    __shared__ unsigned sbuf[2048];
    __shared__ int gaddr[2048];
    __shared__ int csum[256];
    int tid = threadIdx.x;

    // ---- global scan of buktot -> gexc (exclusive) ----
    int g0 = (2 * tid < NBUK) ? buktot[2 * tid] : 0;
    int g1 = (2 * tid + 1 < NBUK) ? buktot[2 * tid + 1] : 0;
    int gsum = g0 + g1;
    csum[tid] = gsum;
    __syncthreads();
    for (int o2 = 1; o2 < 256; o2 <<= 1) {
        int t = (tid >= o2) ? csum[tid - o2] : 0;
        __syncthreads();
        csum[tid] += t;
        __syncthreads();
    }
    int gex = csum[tid] - gsum;
    if (2 * tid < NBUK) gexc[2 * tid] = gex;
    if (2 * tid + 1 < NBUK) gexc[2 * tid + 1] = gex + g0;
    __syncthreads();
    if (blockIdx.x == 0) {
        for (int i = tid; i < NBUK; i += 256) bukstart[i] = gexc[i];
        if (tid == 0) { bukstart[NBUK] = E; rowptr[N_NODES] = E; }
    }

    // ---- per-block histogram ----
    for (int i = tid; i < NBUK; i += 256) cnt[i] = 0;
    __syncthreads();
    int b0 = blockIdx.x * 2048;
    int sv[8], dv[8], off[8];
#pragma unroll
    for (int j = 0; j < 8; ++j) {
        int i = b0 + j * 256 + tid;
        if (i < E) {
            sv[j] = src[i];
            dv[j] = dst[i];
            off[j] = atomicAdd(&cnt[dv[j] >> 8], 1);
        } else {
            dv[j] = -1; sv[j] = 0; off[j] = 0;
        }
    }
    __syncthreads();
    // ---- local scan of cnt -> seg ----
    int c0 = (2 * tid < NBUK) ? cnt[2 * tid] : 0;
    int c1 = (2 * tid + 1 < NBUK) ? cnt[2 * tid + 1] : 0;
    int psum = c0 + c1;
    csum[tid] = psum;
    __syncthreads();
    for (int o2 = 1; o2 < 256; o2 <<= 1) {
        int t = (tid >= o2) ? csum[tid - o2] : 0;
        __syncthreads();
        csum[tid] += t;
        __syncthreads();
    }
    int pexcl = csum[tid] - psum;
    if (2 * tid < NBUK) seg[2 * tid] = pexcl;
    if (2 * tid + 1 < NBUK) seg[2 * tid + 1] = pexcl + c0;
    __syncthreads();
    // ---- reserve global ranges: gexc + bukcnt2 cursor ----
    for (int i = tid; i < NBUK; i += 256)
        gbase[i] = cnt[i] ? (gexc[i] + atomicAdd(bukcnt2 + i, cnt[i])) : 0;
    __syncthreads();
#pragma unroll
    for (int j = 0; j < 8; ++j) {
        if (dv[j] >= 0) {
            int b = dv[j] >> 8;
            int k = seg[b] + off[j];
            sbuf[k] = (unsigned)sv[j] | ((unsigned)(dv[j] & 255) << 17);
            gaddr[k] = gbase[b] + off[j];
        }
    }
    __syncthreads();
    int tot = E - b0; if (tot > 2048) tot = 2048;
    for (int k = tid; k < tot; k += 256)
        pair[gaddr[k]] = sbuf[k];
}

// ---------------- bucketC: LDS-cached pair, rowptr + csr scatter -----------
__global__ __launch_bounds__(256) void k_bucketC(const unsigned* __restrict__ pair,
                                                 const int* __restrict__ bukstart,
                                                 int* __restrict__ rowptr,
                                                 int* __restrict__ csr, int E) {
    __shared__ int cnt[256];
    __shared__ int s[256];
    __shared__ int wofs[256];
    __shared__ unsigned sp[BC_CAP];
    int buk = blockIdx.x, tid = threadIdx.x;
    int p0 = bukstart[buk], p1 = bukstart[buk + 1];
    int len = p1 - p0;
    bool fits = (len <= BC_CAP);
    cnt[tid] = 0;
    __syncthreads();
    for (int i = p0 + tid; i < p1; i += 256) {
        unsigned v = pair[i];
        if (fits) sp[i - p0] = v;
        atomicAdd(&cnt[v >> 17], 1);
    }
    __syncthreads();
    int v = cnt[tid];
    s[tid] = v;
    __syncthreads();
    for (int off = 1; off < 256; off <<= 1) {
        int t = (tid >= off) ? s[tid - off] : 0;
        __syncthreads();
        s[tid] += t;
        __syncthreads();
    }
    int r = p0 + s[tid] - v;
    wofs[tid] = r;
    int node = (buk << 8) + tid;
    if (node < N_NODES) rowptr[node] = r;
    __syncthreads();
    for (int i = p0 + tid; i < p1; i += 256) {
        unsigned p = fits ? sp[i - p0] : pair[i];
        int pos = atomicAdd(&wofs[p >> 17], 1);
        csr[pos] = (int)(p & 0x1FFFFu);
    }
}

// ---------------- Aggregation: 8 edges/wave, dot2 inner loop ---------------
__global__ __launch_bounds__(256) void k_agg(const int* __restrict__ rowptr,
                                             const int* __restrict__ csr,
                                             const float* __restrict__ el,
                                             const float* __restrict__ er,
                                             const __half* __restrict__ feat,
                                             const float* __restrict__ bias,
                                             __half* __restrict__ agg) {
    int tid = threadIdx.x;
    int wave = tid >> 6, lane = tid & 63;
    int slot = lane >> 3;          // edge slot 0..7
    int fl = lane & 7;             // feature octet
    int bid = blockIdx.x;          // 25000 = 8 * 3125 -> bijective XCD swizzle
    int swz = (bid & 7) * 3125 + (bid >> 3);
    int n = swz * 4 + wave;
    if (n >= N_NODES) return;
    int h = fl >> 1;
    float ern = er[(size_t)n * 4 + h];
    int e0 = rowptr[n], e1 = rowptr[n + 1];
    float acc[8] = {0.f, 0.f, 0.f, 0.f, 0.f, 0.f, 0.f, 0.f};
    float den = 0.f;
    const f16x2 one2 = {(_Float16)1.f, (_Float16)1.f};
    int e = e0 + slot;
    for (; e + 8 < e1; e += 16) {
        int s0 = csr[e], s1 = csr[e + 8];
        f16x8 v0 = *(const f16x8*)(feat + (size_t)s0 * 64 + fl * 8);
        f16x8 v1 = *(const f16x8*)(feat + (size_t)s1 * 64 + fl * 8);
        float ev0 = el[(size_t)s0 * 4 + h] + ern;
        float ev1 = el[(size_t)s1 * 4 + h] + ern;
        ev0 = ev0 > 0.f ? ev0 : 0.2f * ev0;
        ev1 = ev1 > 0.f ? ev1 : 0.2f * ev1;
        float ez0 = __builtin_amdgcn_exp2f(ev0);
        float ez1 = __builtin_amdgcn_exp2f(ev1);
        f16x2 ezp = {(_Float16)ez0, (_Float16)ez1};
#pragma unroll
        for (int t = 0; t < 8; ++t) {
            f16x2 p = {v0[t], v1[t]};
            acc[t] = __builtin_amdgcn_fdot2(p, ezp, acc[t], false);
        }
        den = __builtin_amdgcn_fdot2(one2, ezp, den, false);
    }
    for (; e < e1; e += 8) {
        int s0 = csr[e];
        f16x8 v0 = *(const f16x8*)(feat + (size_t)s0 * 64 + fl * 8);
        float ev0 = el[(size_t)s0 * 4 + h] + ern;
        ev0 = ev0 > 0.f ? ev0 : 0.2f * ev0;
        float ez0 = __builtin_amdgcn_exp2f(ev0);
#pragma unroll
        for (int t = 0; t < 8; ++t)
            acc[t] += ez0 * (float)v0[t];
        den += ez0;
    }
#pragma unroll
    for (int t = 0; t < 8; ++t) {
        acc[t] += __shfl_xor(acc[t], 32);
        acc[t] += __shfl_xor(acc[t], 16);
        acc[t] += __shfl_xor(acc[t], 8);
    }
    den += __shfl_xor(den, 32);
    den += __shfl_xor(den, 16);
    den += __shfl_xor(den, 8);
    if (slot == 0) {
        float inv = 1.f / den;
        s16x8 o;
#pragma unroll
        for (int t = 0; t < 8; ++t)
            o[t] = f2h(acc[t] * inv + bias[fl * 8 + t]);
        *(s16x8*)(agg + (size_t)n * 64 + fl * 8) = o;
    }
}

// ---------------- MFMA MLP v3 — fp16 end-to-end, 16 paths/block ------------
template <int KS, int CT>
__device__ __forceinline__ void mfma_layer16(const short* sa, int sstride,
                                             short* dst_,
                                             const short* __restrict__ wf,
                                             const float* __restrict__ bias,
                                             int dout, int w, int l) {
    int abase = (l & 15) * sstride + ((l >> 4) * 8);
    int c_lane = l & 15;
    for (int ct = w; ct < CT; ct += 4) {
        f32x4 acc = {0.f, 0.f, 0.f, 0.f};
        const f16x8* wp = (const f16x8*)wf + (size_t)(ct * KS) * 64 + l;
#pragma unroll
        for (int ks = 0; ks < KS; ++ks) {
            f16x8 av = *(const f16x8*)(sa + abase + ks * 32);
            f16x8 wv = wp[ks * 64];
            acc = __builtin_amdgcn_mfma_f32_16x16x32_f16(av, wv, acc, 0, 0, 0);
        }
        int c = ct * 16 + c_lane;
        float bb = (c < dout) ? bias[c] : 0.f;
        int row0 = (l >> 4) * 4;
#pragma unroll
        for (int j = 0; j < 4; ++j) {
            float v = acc[j] + bb;
            v = v > 0.f ? v : 0.f;
            dst_[(row0 + j) * 200 + c] = f2h(v);
        }
    }
}

__global__ __launch_bounds__(256) void k_mlp(const __half* __restrict__ agg,
                                             const short* __restrict__ wf,
                                             const float* __restrict__ b1,
                                             const float* __restrict__ b2,
                                             const float* __restrict__ b3,
                                             const float* __restrict__ b4,
                                             const float* __restrict__ b5,
                                             const float* __restrict__ b6,
                                             const float* __restrict__ w7,
                                             const float* __restrict__ b7,
                                             const float* __restrict__ wt,
                                             float* __restrict__ outp) {
    __shared__ __align__(16) short smem[13600];
    __shared__ float wx[16];
    short* g  = smem;           // [16][648] fp16
    short* h0 = smem + 10368;   // [16][200]
    short* h1 = smem;           // overlays g (dead after L1)

    int tid = threadIdx.x;
    int w = tid >> 6, l = tid & 63;
    int p0 = blockIdx.x * 16;

    const s16x8* a8 = (const s16x8*)(agg + (size_t)p0 * 640);
    for (int i = tid; i < 16 * 80; i += 256) {
        int r = i / 80, c8 = (i % 80) * 8;
        *(s16x8*)(g + r * 648 + c8) = a8[i];
    }

    if (tid < 128) {
        int path = tid >> 3, sub = tid & 7;
        const __half* gr = agg + (size_t)(p0 + path) * 640;
        float acc = 0.f;
        for (int k = sub * 4; k < 640; k += 32) {
            s16x4 gv = *(const s16x4*)(gr + k);
            float4 wv = *(const float4*)(wt + k);
            acc += h2f(gv[0]) * wv.x + h2f(gv[1]) * wv.y
                 + h2f(gv[2]) * wv.z + h2f(gv[3]) * wv.w;
        }
        acc += __shfl_xor(acc, 1);
        acc += __shfl_xor(acc, 2);
        acc += __shfl_xor(acc, 4);
        if (sub == 0) wx[path] = acc;
    }
    __syncthreads();

    mfma_layer16<20, 12>(g, 648, h0, wf + 0,      b1, 180, w, l);
    __syncthreads();
    mfma_layer16<6, 10>(h0, 200, h1, wf + 122880, b2, 150, w, l);
    __syncthreads();
    mfma_layer16<5, 8>(h1, 200, h0, wf + 153600, b3, 128, w, l);
    __syncthreads();
    mfma_layer16<4, 5>(h0, 200, h1, wf + 174080, b4, 80, w, l);
    {
        int r = tid >> 4, c = 80 + (tid & 15);
        h1[r * 200 + c] = 0;
    }
    __syncthreads();
    mfma_layer16<3, 4>(h1, 200, h0, wf + 184320, b5, 64, w, l);
    __syncthreads();
    mfma_layer16<2, 2>(h0, 200, h1, wf + 190464, b6, 32, w, l);
    __syncthreads();

    if (tid < 16) {
        float acc = b7[0];
#pragma unroll
        for (int k = 0; k < 32; ++k)
            acc += h2f(h1[tid * 200 + k]) * w7[k];
        outp[p0 + tid] = acc + wx[tid];
    }
}

extern "C" void kernel_launch(void* const* d_in, const int* in_sizes, int n_in,
                              void* d_out, int out_size, void* d_ws, size_t ws_size,
                              hipStream_t stream) {
    const float* x      = (const float*)d_in[0];
    const int*   src    = (const int*)d_in[1];
    const int*   dst    = (const int*)d_in[2];
    const float* fc_w   = (const float*)d_in[3];
    const float* bias   = (const float*)d_in[4];
    const float* attn_l = (const float*)d_in[5];
    const float* attn_r = (const float*)d_in[6];
    const float* w1 = (const float*)d_in[7];  const float* b1 = (const float*)d_in[8];
    const float* w2 = (const float*)d_in[9];  const float* b2 = (const float*)d_in[10];
    const float* w3 = (const float*)d_in[11]; const float* b3 = (const float*)d_in[12];
    const float* w4 = (const float*)d_in[13]; const float* b4 = (const float*)d_in[14];
    const float* w5 = (const float*)d_in[15]; const float* b5 = (const float*)d_in[16];
    const float* w6 = (const float*)d_in[17]; const float* b6 = (const float*)d_in[18];
    const float* w7 = (const float*)d_in[19]; const float* b7 = (const float*)d_in[20];
    const float* wt = (const float*)d_in[21];
    int E = in_sizes[1];

    float* ws      = (float*)d_ws;
    __half* feat   = (__half*)ws;               // 6.4M fp16
    float* el      = ws + 6400000;              //   400,000 f
    float* er      = ws + 6800000;              //   400,000 f
    __half* agg    = (__half*)(ws + 7200000);   // 6.4M fp16
    unsigned* pair = (unsigned*)(ws + 10400000);// E u32
    int*   rowptr  = (int*)(ws + 13600000);     //   100,001 i (pad 100,004)
    int*   buktot  = (int*)(ws + 13700004);     //       391 i
    int*   bukcnt2 = (int*)(ws + 13700395);     //       391 i (contiguous w/ buktot)
    int*   bukstart= (int*)(ws + 13700800);     //       392 i
    int*   csr     = (int*)(ws + 13701200);     //         E i
    short* wf      = (short*)(ws + 13701200 + E); // 192,512 fp16

    int nwgA = (E + 2047) / 2048;

    hipMemsetAsync(buktot, 0, 2 * NBUK * 4, stream);   // buktot + bukcnt2

    k_fused1<<<FEAT_BLKS + HIST_BLKS + WPREP_BLKS, 256, 0, stream>>>(
        x, fc_w, attn_l, attn_r, feat, el, er, dst, buktot,
        w1, w2, w3, w4, w5, w6, wf, E);
    k_bucketA<<<nwgA, 256, 0, stream>>>(src, dst, buktot, bukcnt2, bukstart,
                                        rowptr, pair, E);
    k_bucketC<<<NBUK, 256, 0, stream>>>(pair, bukstart, rowptr, csr, E);
    k_agg<<<N_NODES / 4, 256, 0, stream>>>(rowptr, csr, el, er, feat, bias, agg);
    k_mlp<<<P_PATHS / 16, 256, 0, stream>>>(agg, wf, b1, b2, b3, b4, b5, b6,
                                            w7, b7, wt, (float*)d_out);
}

// Round 20
// 157.175 us; speedup vs baseline: 1.0565x; 1.0565x over previous
//
#include <hip/hip_runtime.h>
#include <hip/hip_bf16.h>
#include <hip/hip_fp16.h>

#define N_NODES 100000
#define P_PATHS 10000
#define NBUK 391          // ceil(100000/256), bucket = dst>>8
#define FEAT_BLKS 782     // 128 nodes/block
#define HIST_BLKS 416     // 416*4096 >= E
#define WPREP_BLKS 94     // 94*4 = 376 wprep units
#define LOG2E 1.4426950408889634f
#define BC_CAP 5120       // bucketC LDS pair cache (20KB)

typedef __attribute__((ext_vector_type(8))) short s16x8;
typedef __attribute__((ext_vector_type(4))) short s16x4;
typedef __attribute__((ext_vector_type(4))) float f32x4;
typedef __attribute__((ext_vector_type(8))) _Float16 f16x8;
typedef __attribute__((ext_vector_type(2))) _Float16 f16x2;

__device__ __forceinline__ float h2f(short s) {
    return __half2float(__builtin_bit_cast(__half, s));
}
__device__ __forceinline__ short f2h(float v) {
    return __builtin_bit_cast(short, __float2half(v));
}

// ================= Fused: feat-MFMA(fp16) | bucket-hist | weight-prep ======
__global__ __launch_bounds__(256) void k_fused1(const float* __restrict__ x,
                                                const float* __restrict__ fc_w,
                                                const float* __restrict__ attn_l,
                                                const float* __restrict__ attn_r,
                                                __half* __restrict__ feat,
                                                float* __restrict__ el,
                                                float* __restrict__ er,
                                                const int* __restrict__ dst,
                                                int* __restrict__ buktot,
                                                const float* __restrict__ w1,
                                                const float* __restrict__ w2,
                                                const float* __restrict__ w3,
                                                const float* __restrict__ w4,
                                                const float* __restrict__ w5,
                                                const float* __restrict__ w6,
                                                short* __restrict__ wf, int E) {
    __shared__ float s_w[64 * 64];
    __shared__ float s_wx[64 * 16];
    __shared__ int hcnt[NBUK];
    int tid = threadIdx.x;
    int bb = blockIdx.x;

    if (bb < FEAT_BLKS) {
        // ---- feat = x@fc_w, fp16 MFMA (feat stored fp16 anyway), 128 nodes
        for (int i = tid; i < 4096; i += 256) s_w[i] = fc_w[i];
        __syncthreads();
        for (int i = tid; i < 1024; i += 256) {
            int k = i >> 4, c = i & 15;
            float v = 0.f;
            if (c < 8) {
                int h = c & 3;
                const float* av = (c < 4) ? attn_l : attn_r;
                for (int f = 0; f < 16; ++f) v += s_w[k * 64 + h * 16 + f] * av[h * 16 + f];
            }
            s_wx[i] = v * LOG2E;   // prescale -> k_agg uses raw v_exp_f32
        }
        __syncthreads();

        int w = tid >> 6, l = tid & 63;
        int c_lane = l & 15, kg = l >> 4;

        f16x8 wfr[5][2];
#pragma unroll
        for (int ct = 0; ct < 5; ++ct)
#pragma unroll
            for (int ks = 0; ks < 2; ++ks) {
                f16x8 h8;
#pragma unroll
                for (int i = 0; i < 8; ++i) {
                    int k = ks * 32 + kg * 8 + i;
                    float v = (ct < 4) ? s_w[k * 64 + ct * 16 + c_lane]
                                       : s_wx[k * 16 + c_lane];
                    h8[i] = (_Float16)v;
                }
                wfr[ct][ks] = h8;
            }

        int nbase = bb * 128 + w * 32;
#pragma unroll 1
        for (int mt = 0; mt < 2; ++mt) {
            int m0 = nbase + mt * 16;
            if (m0 >= N_NODES) break;
            int arow = m0 + c_lane;
            size_t axoff = (size_t)(arow < N_NODES ? arow : N_NODES - 1) * 64;
            f16x8 af[2];
#pragma unroll
            for (int ks = 0; ks < 2; ++ks) {
                const float* xp = x + axoff + ks * 32 + kg * 8;
                float4 v0 = *(const float4*)xp;
                float4 v1 = *(const float4*)(xp + 4);
                f16x8 h8;
                h8[0] = (_Float16)v0.x; h8[1] = (_Float16)v0.y;
                h8[2] = (_Float16)v0.z; h8[3] = (_Float16)v0.w;
                h8[4] = (_Float16)v1.x; h8[5] = (_Float16)v1.y;
                h8[6] = (_Float16)v1.z; h8[7] = (_Float16)v1.w;
                af[ks] = h8;
            }
            int r0 = m0 + kg * 4;
#pragma unroll
            for (int ct = 0; ct < 5; ++ct) {
                f32x4 acc = {0.f, 0.f, 0.f, 0.f};
#pragma unroll
                for (int ks = 0; ks < 2; ++ks)
                    acc = __builtin_amdgcn_mfma_f32_16x16x32_f16(af[ks], wfr[ct][ks], acc, 0, 0, 0);
                if (ct < 4) {
#pragma unroll
                    for (int j = 0; j < 4; ++j) {
                        int r = r0 + j;
                        if (r < N_NODES)
                            feat[(size_t)r * 64 + ct * 16 + c_lane] = __float2half(acc[j]);
                    }
                } else {
                    if (c_lane < 4) {
#pragma unroll
                        for (int j = 0; j < 4; ++j) {
                            int r = r0 + j;
                            if (r < N_NODES) el[r * 4 + c_lane] = acc[j];
                        }
                    } else if (c_lane < 8) {
#pragma unroll
                        for (int j = 0; j < 4; ++j) {
                            int r = r0 + j;
                            if (r < N_NODES) er[r * 4 + (c_lane - 4)] = acc[j];
                        }
                    }
                }
            }
        }
    } else if (bb < FEAT_BLKS + HIST_BLKS) {
        // ---------------- bucket histogram (LDS-staged) --------------------
        int hb = bb - FEAT_BLKS;
        for (int i = tid; i < NBUK; i += 256) hcnt[i] = 0;
        __syncthreads();
#pragma unroll
        for (int j = 0; j < 4; ++j) {
            int i = hb * 4096 + j * 1024 + tid * 4;
            if (i + 3 < E) {
                int4 d4 = *(const int4*)(dst + i);
                atomicAdd(&hcnt[d4.x >> 8], 1);
                atomicAdd(&hcnt[d4.y >> 8], 1);
                atomicAdd(&hcnt[d4.z >> 8], 1);
                atomicAdd(&hcnt[d4.w >> 8], 1);
            } else {
                for (int k = i; k < E && k < i + 4; ++k)
                    atomicAdd(&hcnt[dst[k] >> 8], 1);
            }
        }
        __syncthreads();
        for (int i = tid; i < NBUK; i += 256)
            if (hcnt[i]) atomicAdd(buktot + i, hcnt[i]);
    } else {
        // ---------------- weight prep: f32 -> fp16 B-fragments -------------
        const int nblk[6] = {240, 60, 40, 20, 12, 4};
        const int din_[6] = {640, 180, 150, 128, 80, 64};
        const int dout_[6] = {180, 150, 128, 80, 64, 32};
        const int ks_[6]  = {20, 6, 5, 4, 3, 2};
        const int off_[6] = {0, 122880, 153600, 174080, 184320, 190464};
        const float* wp[6] = {w1, w2, w3, w4, w5, w6};

        int b = (bb - FEAT_BLKS - HIST_BLKS) * 4 + (tid >> 6);
        int layer = 0;
        while (layer < 5 && b >= nblk[layer]) { b -= nblk[layer]; ++layer; }
        int KS = ks_[layer];
        int ct = b / KS, ks = b % KS;
        int l = tid & 63;
        int c = ct * 16 + (l & 15);
        int k0 = ks * 32 + ((l >> 4) * 8);
        int din = din_[layer], dout = dout_[layer];
        const float* w = wp[layer];
        s16x8 vh;
#pragma unroll
        for (int i = 0; i < 8; ++i) {
            int k = k0 + i;
            float v = (k < din && c < dout) ? w[k * dout + c] : 0.f;
            vh[i] = f2h(v);
        }
        size_t o = (size_t)off_[layer] + ((size_t)(ct * KS + ks) * 64 + l) * 8;
        *(s16x8*)(wf + o) = vh;
    }
}

// ---------------- scan 391 bucket totals -> bukstart/bukptr ----------------
__global__ __launch_bounds__(512) void k_scanB(const int* __restrict__ buktot,
                                               int* __restrict__ bukstart,
                                               int* __restrict__ bukptr,
                                               int* __restrict__ rowptr, int E) {
    __shared__ int s[512];
    int tid = threadIdx.x;
    int v = (tid < NBUK) ? buktot[tid] : 0;
    s[tid] = v;
    __syncthreads();
    for (int off = 1; off < 512; off <<= 1) {
        int t = (tid >= off) ? s[tid - off] : 0;
        __syncthreads();
        s[tid] += t;
        __syncthreads();
    }
    int excl = s[tid] - v;
    if (tid < NBUK) { bukstart[tid] = excl; bukptr[tid] = excl; }
    if (tid == 0) { bukstart[NBUK] = E; rowptr[N_NODES] = E; }
}

// ---------------- bucketA v2: LDS-sorted coalesced writeout ----------------
// packed word: src (17 bits) | (dst & 255) << 17
__global__ __launch_bounds__(256) void k_bucketA(const int* __restrict__ src,
                                                 const int* __restrict__ dst,
                                                 int* __restrict__ bukptr,
                                                 unsigned* __restrict__ pair, int E) {
    __shared__ int cnt[NBUK];
    __shared__ int seg[NBUK];
    __shared__ int gbase[NBUK];
    __shared__ unsigned sbuf[2048];
    __shared__ int gaddr[2048];
    __shared__ int csum[256];
    int tid = threadIdx.x;
    for (int i = tid; i < NBUK; i += 256) cnt[i] = 0;
    __syncthreads();
    int b0 = blockIdx.x * 2048;
    int sv[8], dv[8], off[8];
#pragma unroll
    for (int j = 0; j < 8; ++j) {
        int i = b0 + j * 256 + tid;
        if (i < E) {
            sv[j] = src[i];
            dv[j] = dst[i];
            off[j] = atomicAdd(&cnt[dv[j] >> 8], 1);
        } else {
            dv[j] = -1; sv[j] = 0; off[j] = 0;
        }
    }
    __syncthreads();
    int c0 = (2 * tid < NBUK) ? cnt[2 * tid] : 0;
    int c1 = (2 * tid + 1 < NBUK) ? cnt[2 * tid + 1] : 0;
    int psum = c0 + c1;
    csum[tid] = psum;
    __syncthreads();
    for (int o2 = 1; o2 < 256; o2 <<= 1) {
        int t = (tid >= o2) ? csum[tid - o2] : 0;
        __syncthreads();
        csum[tid] += t;
        __syncthreads();
    }
    int pexcl = csum[tid] - psum;
    if (2 * tid < NBUK) seg[2 * tid] = pexcl;
    if (2 * tid + 1 < NBUK) seg[2 * tid + 1] = pexcl + c0;
    __syncthreads();
    for (int i = tid; i < NBUK; i += 256)
        gbase[i] = cnt[i] ? atomicAdd(bukptr + i, cnt[i]) : 0;
    __syncthreads();
#pragma unroll
    for (int j = 0; j < 8; ++j) {
        if (dv[j] >= 0) {
            int b = dv[j] >> 8;
            int k = seg[b] + off[j];
            sbuf[k] = (unsigned)sv[j] | ((unsigned)(dv[j] & 255) << 17);
            gaddr[k] = gbase[b] + off[j];
        }
    }
    __syncthreads();
    int tot = E - b0; if (tot > 2048) tot = 2048;
    for (int k = tid; k < tot; k += 256)
        pair[gaddr[k]] = sbuf[k];
}

// ---------------- bucketC: LDS-cached pair, rowptr + csr scatter -----------
__global__ __launch_bounds__(256) void k_bucketC(const unsigned* __restrict__ pair,
                                                 const int* __restrict__ bukstart,
                                                 int* __restrict__ rowptr,
                                                 int* __restrict__ csr, int E) {
    __shared__ int cnt[256];
    __shared__ int s[256];
    __shared__ int wofs[256];
    __shared__ unsigned sp[BC_CAP];
    int buk = blockIdx.x, tid = threadIdx.x;
    int p0 = bukstart[buk], p1 = bukstart[buk + 1];
    int len = p1 - p0;
    bool fits = (len <= BC_CAP);
    cnt[tid] = 0;
    __syncthreads();
    for (int i = p0 + tid; i < p1; i += 256) {
        unsigned v = pair[i];
        if (fits) sp[i - p0] = v;
        atomicAdd(&cnt[v >> 17], 1);
    }
    __syncthreads();
    int v = cnt[tid];
    s[tid] = v;
    __syncthreads();
    for (int off = 1; off < 256; off <<= 1) {
        int t = (tid >= off) ? s[tid - off] : 0;
        __syncthreads();
        s[tid] += t;
        __syncthreads();
    }
    int r = p0 + s[tid] - v;
    wofs[tid] = r;
    int node = (buk << 8) + tid;
    if (node < N_NODES) rowptr[node] = r;
    __syncthreads();
    for (int i = p0 + tid; i < p1; i += 256) {
        unsigned p = fits ? sp[i - p0] : pair[i];
        int pos = atomicAdd(&wofs[p >> 17], 1);
        csr[pos] = (int)(p & 0x1FFFFu);
    }
}

// ---------------- Aggregation: 8 edges/wave, dot2 inner loop ---------------
__global__ __launch_bounds__(256) void k_agg(const int* __restrict__ rowptr,
                                             const int* __restrict__ csr,
                                             const float* __restrict__ el,
                                             const float* __restrict__ er,
                                             const __half* __restrict__ feat,
                                             const float* __restrict__ bias,
                                             __half* __restrict__ agg) {
    int tid = threadIdx.x;
    int wave = tid >> 6, lane = tid & 63;
    int slot = lane >> 3;          // edge slot 0..7
    int fl = lane & 7;             // feature octet
    int bid = blockIdx.x;          // 25000 = 8 * 3125 -> bijective XCD swizzle
    int swz = (bid & 7) * 3125 + (bid >> 3);
    int n = swz * 4 + wave;
    if (n >= N_NODES) return;
    int h = fl >> 1;
    float ern = er[(size_t)n * 4 + h];
    int e0 = rowptr[n], e1 = rowptr[n + 1];
    float acc[8] = {0.f, 0.f, 0.f, 0.f, 0.f, 0.f, 0.f, 0.f};
    float den = 0.f;
    const f16x2 one2 = {(_Float16)1.f, (_Float16)1.f};
    int e = e0 + slot;
    for (; e + 8 < e1; e += 16) {
        int s0 = csr[e], s1 = csr[e + 8];
        f16x8 v0 = *(const f16x8*)(feat + (size_t)s0 * 64 + fl * 8);
        f16x8 v1 = *(const f16x8*)(feat + (size_t)s1 * 64 + fl * 8);
        float ev0 = el[(size_t)s0 * 4 + h] + ern;
        float ev1 = el[(size_t)s1 * 4 + h] + ern;
        ev0 = ev0 > 0.f ? ev0 : 0.2f * ev0;
        ev1 = ev1 > 0.f ? ev1 : 0.2f * ev1;
        float ez0 = __builtin_amdgcn_exp2f(ev0);
        float ez1 = __builtin_amdgcn_exp2f(ev1);
        f16x2 ezp = {(_Float16)ez0, (_Float16)ez1};
#pragma unroll
        for (int t = 0; t < 8; ++t) {
            f16x2 p = {v0[t], v1[t]};
            acc[t] = __builtin_amdgcn_fdot2(p, ezp, acc[t], false);
        }
        den = __builtin_amdgcn_fdot2(one2, ezp, den, false);
    }
    for (; e < e1; e += 8) {
        int s0 = csr[e];
        f16x8 v0 = *(const f16x8*)(feat + (size_t)s0 * 64 + fl * 8);
        float ev0 = el[(size_t)s0 * 4 + h] + ern;
        ev0 = ev0 > 0.f ? ev0 : 0.2f * ev0;
        float ez0 = __builtin_amdgcn_exp2f(ev0);
#pragma unroll
        for (int t = 0; t < 8; ++t)
            acc[t] += ez0 * (float)v0[t];
        den += ez0;
    }
#pragma unroll
    for (int t = 0; t < 8; ++t) {
        acc[t] += __shfl_xor(acc[t], 32);
        acc[t] += __shfl_xor(acc[t], 16);
        acc[t] += __shfl_xor(acc[t], 8);
    }
    den += __shfl_xor(den, 32);
    den += __shfl_xor(den, 16);
    den += __shfl_xor(den, 8);
    if (slot == 0) {
        float inv = 1.f / den;
        s16x8 o;
#pragma unroll
        for (int t = 0; t < 8; ++t)
            o[t] = f2h(acc[t] * inv + bias[fl * 8 + t]);
        *(s16x8*)(agg + (size_t)n * 64 + fl * 8) = o;
    }
}

// ---------------- MFMA MLP v3 — fp16 end-to-end, 16 paths/block ------------
template <int KS, int CT>
__device__ __forceinline__ void mfma_layer16(const short* sa, int sstride,
                                             short* dst_,
                                             const short* __restrict__ wf,
                                             const float* __restrict__ bias,
                                             int dout, int w, int l) {
    int abase = (l & 15) * sstride + ((l >> 4) * 8);
    int c_lane = l & 15;
    for (int ct = w; ct < CT; ct += 4) {
        f32x4 acc = {0.f, 0.f, 0.f, 0.f};
        const f16x8* wp = (const f16x8*)wf + (size_t)(ct * KS) * 64 + l;
#pragma unroll
        for (int ks = 0; ks < KS; ++ks) {
            f16x8 av = *(const f16x8*)(sa + abase + ks * 32);
            f16x8 wv = wp[ks * 64];
            acc = __builtin_amdgcn_mfma_f32_16x16x32_f16(av, wv, acc, 0, 0, 0);
        }
        int c = ct * 16 + c_lane;
        float bb = (c < dout) ? bias[c] : 0.f;
        int row0 = (l >> 4) * 4;
#pragma unroll
        for (int j = 0; j < 4; ++j) {
            float v = acc[j] + bb;
            v = v > 0.f ? v : 0.f;
            dst_[(row0 + j) * 200 + c] = f2h(v);
        }
    }
}

__global__ __launch_bounds__(256) void k_mlp(const __half* __restrict__ agg,
                                             const short* __restrict__ wf,
                                             const float* __restrict__ b1,
                                             const float* __restrict__ b2,
                                             const float* __restrict__ b3,
                                             const float* __restrict__ b4,
                                             const float* __restrict__ b5,
                                             const float* __restrict__ b6,
                                             const float* __restrict__ w7,
                                             const float* __restrict__ b7,
                                             const float* __restrict__ wt,
                                             float* __restrict__ outp) {
    __shared__ __align__(16) short smem[13600];
    __shared__ float wx[16];
    short* g  = smem;           // [16][648] fp16
    short* h0 = smem + 10368;   // [16][200]
    short* h1 = smem;           // overlays g (dead after L1)

    int tid = threadIdx.x;
    int w = tid >> 6, l = tid & 63;
    int p0 = blockIdx.x * 16;

    const s16x8* a8 = (const s16x8*)(agg + (size_t)p0 * 640);
    for (int i = tid; i < 16 * 80; i += 256) {
        int r = i / 80, c8 = (i % 80) * 8;
        *(s16x8*)(g + r * 648 + c8) = a8[i];
    }

    if (tid < 128) {
        int path = tid >> 3, sub = tid & 7;
        const __half* gr = agg + (size_t)(p0 + path) * 640;
        float acc = 0.f;
        for (int k = sub * 4; k < 640; k += 32) {
            s16x4 gv = *(const s16x4*)(gr + k);
            float4 wv = *(const float4*)(wt + k);
            acc += h2f(gv[0]) * wv.x + h2f(gv[1]) * wv.y
                 + h2f(gv[2]) * wv.z + h2f(gv[3]) * wv.w;
        }
        acc += __shfl_xor(acc, 1);
        acc += __shfl_xor(acc, 2);
        acc += __shfl_xor(acc, 4);
        if (sub == 0) wx[path] = acc;
    }
    __syncthreads();

    mfma_layer16<20, 12>(g, 648, h0, wf + 0,      b1, 180, w, l);
    __syncthreads();
    mfma_layer16<6, 10>(h0, 200, h1, wf + 122880, b2, 150, w, l);
    __syncthreads();
    mfma_layer16<5, 8>(h1, 200, h0, wf + 153600, b3, 128, w, l);
    __syncthreads();
    mfma_layer16<4, 5>(h0, 200, h1, wf + 174080, b4, 80, w, l);
    {
        int r = tid >> 4, c = 80 + (tid & 15);
        h1[r * 200 + c] = 0;
    }
    __syncthreads();
    mfma_layer16<3, 4>(h1, 200, h0, wf + 184320, b5, 64, w, l);
    __syncthreads();
    mfma_layer16<2, 2>(h0, 200, h1, wf + 190464, b6, 32, w, l);
    __syncthreads();

    if (tid < 16) {
        float acc = b7[0];
#pragma unroll
        for (int k = 0; k < 32; ++k)
            acc += h2f(h1[tid * 200 + k]) * w7[k];
        outp[p0 + tid] = acc + wx[tid];
    }
}

extern "C" void kernel_launch(void* const* d_in, const int* in_sizes, int n_in,
                              void* d_out, int out_size, void* d_ws, size_t ws_size,
                              hipStream_t stream) {
    const float* x      = (const float*)d_in[0];
    const int*   src    = (const int*)d_in[1];
    const int*   dst    = (const int*)d_in[2];
    const float* fc_w   = (const float*)d_in[3];
    const float* bias   = (const float*)d_in[4];
    const float* attn_l = (const float*)d_in[5];
    const float* attn_r = (const float*)d_in[6];
    const float* w1 = (const float*)d_in[7];  const float* b1 = (const float*)d_in[8];
    const float* w2 = (const float*)d_in[9];  const float* b2 = (const float*)d_in[10];
    const float* w3 = (const float*)d_in[11]; const float* b3 = (const float*)d_in[12];
    const float* w4 = (const float*)d_in[13]; const float* b4 = (const float*)d_in[14];
    const float* w5 = (const float*)d_in[15]; const float* b5 = (const float*)d_in[16];
    const float* w6 = (const float*)d_in[17]; const float* b6 = (const float*)d_in[18];
    const float* w7 = (const float*)d_in[19]; const float* b7 = (const float*)d_in[20];
    const float* wt = (const float*)d_in[21];
    int E = in_sizes[1];

    float* ws      = (float*)d_ws;
    __half* feat   = (__half*)ws;               // 6.4M fp16
    float* el      = ws + 6400000;              //   400,000 f
    float* er      = ws + 6800000;              //   400,000 f
    __half* agg    = (__half*)(ws + 7200000);   // 6.4M fp16
    unsigned* pair = (unsigned*)(ws + 10400000);// E u32
    int*   rowptr  = (int*)(ws + 13600000);     //   100,001 i (pad 100,004)
    int*   buktot  = (int*)(ws + 13700004);     //       391 i
    int*   bukstart= (int*)(ws + 13700400);     //       392 i
    int*   bukptr  = (int*)(ws + 13700800);     //       391 i
    int*   csr     = (int*)(ws + 13701200);     //         E i
    short* wf      = (short*)(ws + 13701200 + E); // 192,512 fp16

    int nwgA = (E + 2047) / 2048;

    hipMemsetAsync(buktot, 0, NBUK * 4, stream);

    k_fused1<<<FEAT_BLKS + HIST_BLKS + WPREP_BLKS, 256, 0, stream>>>(
        x, fc_w, attn_l, attn_r, feat, el, er, dst, buktot,
        w1, w2, w3, w4, w5, w6, wf, E);
    k_scanB<<<1, 512, 0, stream>>>(buktot, bukstart, bukptr, rowptr, E);
    k_bucketA<<<nwgA, 256, 0, stream>>>(src, dst, bukptr, pair, E);
    k_bucketC<<<NBUK, 256, 0, stream>>>(pair, bukstart, rowptr, csr, E);
    k_agg<<<N_NODES / 4, 256, 0, stream>>>(rowptr, csr, el, er, feat, bias, agg);
    k_mlp<<<P_PATHS / 16, 256, 0, stream>>>(agg, wf, b1, b2, b3, b4, b5, b6,
                                            w7, b7, wt, (float*)d_out);
}

// Round 21
// 154.383 us; speedup vs baseline: 1.0756x; 1.0181x over previous
//
#include <hip/hip_runtime.h>
#include <hip/hip_bf16.h>
#include <hip/hip_fp16.h>

#define N_NODES 100000
#define P_PATHS 10000
#define NBUK 391          // ceil(100000/256), bucket = dst>>8
#define FEAT_BLKS 782     // 128 nodes/block
#define HIST_BLKS 416     // 416*4096 >= E
#define WPREP_BLKS 94     // 94*4 = 376 wprep units
#define LOG2E 1.4426950408889634f
#define BC_CAP 5120       // bucketC LDS pair cache (20KB)

typedef __attribute__((ext_vector_type(8))) short s16x8;
typedef __attribute__((ext_vector_type(4))) short s16x4;
typedef __attribute__((ext_vector_type(4))) float f32x4;
typedef __attribute__((ext_vector_type(8))) _Float16 f16x8;
typedef __attribute__((ext_vector_type(2))) _Float16 f16x2;

__device__ __forceinline__ short f2bf(float v) {
    return __builtin_bit_cast(short, __float2bfloat16(v));
}
__device__ __forceinline__ float bf2f(short s) {
    return __bfloat162float(__builtin_bit_cast(__hip_bfloat16, s));
}
__device__ __forceinline__ float h2f(short s) {
    return __half2float(__builtin_bit_cast(__half, s));
}
__device__ __forceinline__ short f2h(float v) {
    return __builtin_bit_cast(short, __float2half(v));
}

// ================= Fused: feat-MFMA | bucket-histogram | weight-prep =======
__global__ __launch_bounds__(256) void k_fused1(const float* __restrict__ x,
                                                const float* __restrict__ fc_w,
                                                const float* __restrict__ attn_l,
                                                const float* __restrict__ attn_r,
                                                __half* __restrict__ feat,
                                                float* __restrict__ el,
                                                float* __restrict__ er,
                                                const int* __restrict__ dst,
                                                int* __restrict__ buktot,
                                                const float* __restrict__ w1,
                                                const float* __restrict__ w2,
                                                const float* __restrict__ w3,
                                                const float* __restrict__ w4,
                                                const float* __restrict__ w5,
                                                const float* __restrict__ w6,
                                                short* __restrict__ wf, int E) {
    __shared__ float s_w[64 * 64];
    __shared__ float s_wx[64 * 16];
    __shared__ int hcnt[NBUK];
    int tid = threadIdx.x;
    int bb = blockIdx.x;

    if (bb < FEAT_BLKS) {
        for (int i = tid; i < 4096; i += 256) s_w[i] = fc_w[i];
        __syncthreads();
        for (int i = tid; i < 1024; i += 256) {
            int k = i >> 4, c = i & 15;
            float v = 0.f;
            if (c < 8) {
                int h = c & 3;
                const float* av = (c < 4) ? attn_l : attn_r;
                for (int f = 0; f < 16; ++f) v += s_w[k * 64 + h * 16 + f] * av[h * 16 + f];
            }
            s_wx[i] = v * LOG2E;   // prescale -> k_agg uses raw v_exp_f32
        }
        __syncthreads();

        int w = tid >> 6, l = tid & 63;
        int c_lane = l & 15, kg = l >> 4;

        s16x8 wh[5][2], wlo[5][2];
#pragma unroll
        for (int ct = 0; ct < 5; ++ct)
#pragma unroll
            for (int ks = 0; ks < 2; ++ks) {
                s16x8 h8, l8;
#pragma unroll
                for (int i = 0; i < 8; ++i) {
                    int k = ks * 32 + kg * 8 + i;
                    float v = (ct < 4) ? s_w[k * 64 + ct * 16 + c_lane]
                                       : s_wx[k * 16 + c_lane];
                    short hi = f2bf(v);
                    h8[i] = hi;
                    l8[i] = f2bf(v - bf2f(hi));
                }
                wh[ct][ks] = h8;
                wlo[ct][ks] = l8;
            }

        int nbase = bb * 128 + w * 32;
#pragma unroll 1
        for (int mt = 0; mt < 2; ++mt) {
            int m0 = nbase + mt * 16;
            if (m0 >= N_NODES) break;
            int arow = m0 + c_lane;
            size_t axoff = (size_t)(arow < N_NODES ? arow : N_NODES - 1) * 64;
            s16x8 ah[2], alo[2];
#pragma unroll
            for (int ks = 0; ks < 2; ++ks) {
                const float* xp = x + axoff + ks * 32 + kg * 8;
                float4 v0 = *(const float4*)xp;
                float4 v1 = *(const float4*)(xp + 4);
                float vv[8] = {v0.x, v0.y, v0.z, v0.w, v1.x, v1.y, v1.z, v1.w};
                s16x8 h8, l8;
#pragma unroll
                for (int i = 0; i < 8; ++i) {
                    short hi = f2bf(vv[i]);
                    h8[i] = hi;
                    l8[i] = f2bf(vv[i] - bf2f(hi));
                }
                ah[ks] = h8;
                alo[ks] = l8;
            }
            int r0 = m0 + kg * 4;
#pragma unroll
            for (int ct = 0; ct < 5; ++ct) {
                f32x4 acc = {0.f, 0.f, 0.f, 0.f};
#pragma unroll
                for (int ks = 0; ks < 2; ++ks) {
                    acc = __builtin_amdgcn_mfma_f32_16x16x32_bf16(ah[ks], wh[ct][ks], acc, 0, 0, 0);
                    acc = __builtin_amdgcn_mfma_f32_16x16x32_bf16(ah[ks], wlo[ct][ks], acc, 0, 0, 0);
                    acc = __builtin_amdgcn_mfma_f32_16x16x32_bf16(alo[ks], wh[ct][ks], acc, 0, 0, 0);
                }
                if (ct < 4) {
#pragma unroll
                    for (int j = 0; j < 4; ++j) {
                        int r = r0 + j;
                        if (r < N_NODES)
                            feat[(size_t)r * 64 + ct * 16 + c_lane] = __float2half(acc[j]);
                    }
                } else {
                    if (c_lane < 4) {
#pragma unroll
                        for (int j = 0; j < 4; ++j) {
                            int r = r0 + j;
                            if (r < N_NODES) el[r * 4 + c_lane] = acc[j];
                        }
                    } else if (c_lane < 8) {
#pragma unroll
                        for (int j = 0; j < 4; ++j) {
                            int r = r0 + j;
                            if (r < N_NODES) er[r * 4 + (c_lane - 4)] = acc[j];
                        }
                    }
                }
            }
        }
    } else if (bb < FEAT_BLKS + HIST_BLKS) {
        int hb = bb - FEAT_BLKS;
        for (int i = tid; i < NBUK; i += 256) hcnt[i] = 0;
        __syncthreads();
#pragma unroll
        for (int j = 0; j < 4; ++j) {
            int i = hb * 4096 + j * 1024 + tid * 4;
            if (i + 3 < E) {
                int4 d4 = *(const int4*)(dst + i);
                atomicAdd(&hcnt[d4.x >> 8], 1);
                atomicAdd(&hcnt[d4.y >> 8], 1);
                atomicAdd(&hcnt[d4.z >> 8], 1);
                atomicAdd(&hcnt[d4.w >> 8], 1);
            } else {
                for (int k = i; k < E && k < i + 4; ++k)
                    atomicAdd(&hcnt[dst[k] >> 8], 1);
            }
        }
        __syncthreads();
        for (int i = tid; i < NBUK; i += 256)
            if (hcnt[i]) atomicAdd(buktot + i, hcnt[i]);
    } else {
        const int nblk[6] = {240, 60, 40, 20, 12, 4};
        const int din_[6] = {640, 180, 150, 128, 80, 64};
        const int dout_[6] = {180, 150, 128, 80, 64, 32};
        const int ks_[6]  = {20, 6, 5, 4, 3, 2};
        const int off_[6] = {0, 122880, 153600, 174080, 184320, 190464};
        const float* wp[6] = {w1, w2, w3, w4, w5, w6};

        int b = (bb - FEAT_BLKS - HIST_BLKS) * 4 + (tid >> 6);
        int layer = 0;
        while (layer < 5 && b >= nblk[layer]) { b -= nblk[layer]; ++layer; }
        int KS = ks_[layer];
        int ct = b / KS, ks = b % KS;
        int l = tid & 63;
        int c = ct * 16 + (l & 15);
        int k0 = ks * 32 + ((l >> 4) * 8);
        int din = din_[layer], dout = dout_[layer];
        const float* w = wp[layer];
        s16x8 vh;
#pragma unroll
        for (int i = 0; i < 8; ++i) {
            int k = k0 + i;
            float v = (k < din && c < dout) ? w[k * dout + c] : 0.f;
            vh[i] = f2h(v);
        }
        size_t o = (size_t)off_[layer] + ((size_t)(ct * KS + ks) * 64 + l) * 8;
        *(s16x8*)(wf + o) = vh;
    }
}

// ---------------- scan 391 bucket totals -> bukstart/bukptr ----------------
__global__ __launch_bounds__(512) void k_scanB(const int* __restrict__ buktot,
                                               int* __restrict__ bukstart,
                                               int* __restrict__ bukptr,
                                               int* __restrict__ rowptr, int E) {
    __shared__ int s[512];
    int tid = threadIdx.x;
    int v = (tid < NBUK) ? buktot[tid] : 0;
    s[tid] = v;
    __syncthreads();
    for (int off = 1; off < 512; off <<= 1) {
        int t = (tid >= off) ? s[tid - off] : 0;
        __syncthreads();
        s[tid] += t;
        __syncthreads();
    }
    int excl = s[tid] - v;
    if (tid < NBUK) { bukstart[tid] = excl; bukptr[tid] = excl; }
    if (tid == 0) { bukstart[NBUK] = E; rowptr[N_NODES] = E; }
}

// ---------------- bucketA v2: LDS-sorted coalesced writeout ----------------
// packed word: src (17 bits) | (dst & 255) << 17
__global__ __launch_bounds__(256) void k_bucketA(const int* __restrict__ src,
                                                 const int* __restrict__ dst,
                                                 int* __restrict__ bukptr,
                                                 unsigned* __restrict__ pair, int E) {
    __shared__ int cnt[NBUK];
    __shared__ int seg[NBUK];
    __shared__ int gbase[NBUK];
    __shared__ unsigned sbuf[2048];
    __shared__ int gaddr[2048];
    __shared__ int csum[256];
    int tid = threadIdx.x;
    for (int i = tid; i < NBUK; i += 256) cnt[i] = 0;
    __syncthreads();
    int b0 = blockIdx.x * 2048;
    int sv[8], dv[8], off[8];
#pragma unroll
    for (int j = 0; j < 8; ++j) {
        int i = b0 + j * 256 + tid;
        if (i < E) {
            sv[j] = src[i];
            dv[j] = dst[i];
            off[j] = atomicAdd(&cnt[dv[j] >> 8], 1);
        } else {
            dv[j] = -1; sv[j] = 0; off[j] = 0;
        }
    }
    __syncthreads();
    int c0 = (2 * tid < NBUK) ? cnt[2 * tid] : 0;
    int c1 = (2 * tid + 1 < NBUK) ? cnt[2 * tid + 1] : 0;
    int psum = c0 + c1;
    csum[tid] = psum;
    __syncthreads();
    for (int o2 = 1; o2 < 256; o2 <<= 1) {
        int t = (tid >= o2) ? csum[tid - o2] : 0;
        __syncthreads();
        csum[tid] += t;
        __syncthreads();
    }
    int pexcl = csum[tid] - psum;
    if (2 * tid < NBUK) seg[2 * tid] = pexcl;
    if (2 * tid + 1 < NBUK) seg[2 * tid + 1] = pexcl + c0;
    __syncthreads();
    for (int i = tid; i < NBUK; i += 256)
        gbase[i] = cnt[i] ? atomicAdd(bukptr + i, cnt[i]) : 0;
    __syncthreads();
#pragma unroll
    for (int j = 0; j < 8; ++j) {
        if (dv[j] >= 0) {
            int b = dv[j] >> 8;
            int k = seg[b] + off[j];
            sbuf[k] = (unsigned)sv[j] | ((unsigned)(dv[j] & 255) << 17);
            gaddr[k] = gbase[b] + off[j];
        }
    }
    __syncthreads();
    int tot = E - b0; if (tot > 2048) tot = 2048;
    for (int k = tid; k < tot; k += 256)
        pair[gaddr[k]] = sbuf[k];
}

// ---------------- bucketC: LDS-cached pair, rowptr + csr scatter -----------
__global__ __launch_bounds__(256) void k_bucketC(const unsigned* __restrict__ pair,
                                                 const int* __restrict__ bukstart,
                                                 int* __restrict__ rowptr,
                                                 int* __restrict__ csr, int E) {
    __shared__ int cnt[256];
    __shared__ int s[256];
    __shared__ int wofs[256];
    __shared__ unsigned sp[BC_CAP];
    int buk = blockIdx.x, tid = threadIdx.x;
    int p0 = bukstart[buk], p1 = bukstart[buk + 1];
    int len = p1 - p0;
    bool fits = (len <= BC_CAP);
    cnt[tid] = 0;
    __syncthreads();
    for (int i = p0 + tid; i < p1; i += 256) {
        unsigned v = pair[i];
        if (fits) sp[i - p0] = v;
        atomicAdd(&cnt[v >> 17], 1);
    }
    __syncthreads();
    int v = cnt[tid];
    s[tid] = v;
    __syncthreads();
    for (int off = 1; off < 256; off <<= 1) {
        int t = (tid >= off) ? s[tid - off] : 0;
        __syncthreads();
        s[tid] += t;
        __syncthreads();
    }
    int r = p0 + s[tid] - v;
    wofs[tid] = r;
    int node = (buk << 8) + tid;
    if (node < N_NODES) rowptr[node] = r;
    __syncthreads();
    for (int i = p0 + tid; i < p1; i += 256) {
        unsigned p = fits ? sp[i - p0] : pair[i];
        int pos = atomicAdd(&wofs[p >> 17], 1);
        csr[pos] = (int)(p & 0x1FFFFu);
    }
}

// ---------------- Aggregation: 8 edges/wave, dot2 inner loop ---------------
__global__ __launch_bounds__(256) void k_agg(const int* __restrict__ rowptr,
                                             const int* __restrict__ csr,
                                             const float* __restrict__ el,
                                             const float* __restrict__ er,
                                             const __half* __restrict__ feat,
                                             const float* __restrict__ bias,
                                             __half* __restrict__ agg) {
    int tid = threadIdx.x;
    int wave = tid >> 6, lane = tid & 63;
    int slot = lane >> 3;          // edge slot 0..7
    int fl = lane & 7;             // feature octet
    int bid = blockIdx.x;          // 25000 = 8 * 3125 -> bijective XCD swizzle
    int swz = (bid & 7) * 3125 + (bid >> 3);
    int n = swz * 4 + wave;
    if (n >= N_NODES) return;
    int h = fl >> 1;
    float ern = er[(size_t)n * 4 + h];
    int e0 = rowptr[n], e1 = rowptr[n + 1];
    float acc[8] = {0.f, 0.f, 0.f, 0.f, 0.f, 0.f, 0.f, 0.f};
    float den = 0.f;
    const f16x2 one2 = {(_Float16)1.f, (_Float16)1.f};
    int e = e0 + slot;
    for (; e + 8 < e1; e += 16) {
        int s0 = csr[e], s1 = csr[e + 8];
        f16x8 v0 = *(const f16x8*)(feat + (size_t)s0 * 64 + fl * 8);
        f16x8 v1 = *(const f16x8*)(feat + (size_t)s1 * 64 + fl * 8);
        float ev0 = el[(size_t)s0 * 4 + h] + ern;
        float ev1 = el[(size_t)s1 * 4 + h] + ern;
        ev0 = ev0 > 0.f ? ev0 : 0.2f * ev0;
        ev1 = ev1 > 0.f ? ev1 : 0.2f * ev1;
        float ez0 = __builtin_amdgcn_exp2f(ev0);
        float ez1 = __builtin_amdgcn_exp2f(ev1);
        f16x2 ezp = {(_Float16)ez0, (_Float16)ez1};
#pragma unroll
        for (int t = 0; t < 8; ++t) {
            f16x2 p = {v0[t], v1[t]};
            acc[t] = __builtin_amdgcn_fdot2(p, ezp, acc[t], false);
        }
        den = __builtin_amdgcn_fdot2(one2, ezp, den, false);
    }
    for (; e < e1; e += 8) {
        int s0 = csr[e];
        f16x8 v0 = *(const f16x8*)(feat + (size_t)s0 * 64 + fl * 8);
        float ev0 = el[(size_t)s0 * 4 + h] + ern;
        ev0 = ev0 > 0.f ? ev0 : 0.2f * ev0;
        float ez0 = __builtin_amdgcn_exp2f(ev0);
#pragma unroll
        for (int t = 0; t < 8; ++t)
            acc[t] += ez0 * (float)v0[t];
        den += ez0;
    }
#pragma unroll
    for (int t = 0; t < 8; ++t) {
        acc[t] += __shfl_xor(acc[t], 32);
        acc[t] += __shfl_xor(acc[t], 16);
        acc[t] += __shfl_xor(acc[t], 8);
    }
    den += __shfl_xor(den, 32);
    den += __shfl_xor(den, 16);
    den += __shfl_xor(den, 8);
    if (slot == 0) {
        float inv = 1.f / den;
        s16x8 o;
#pragma unroll
        for (int t = 0; t < 8; ++t)
            o[t] = f2h(acc[t] * inv + bias[fl * 8 + t]);
        *(s16x8*)(agg + (size_t)n * 64 + fl * 8) = o;
    }
}

// ---------------- MFMA MLP v3 — fp16 end-to-end, 16 paths/block ------------
template <int KS, int CT>
__device__ __forceinline__ void mfma_layer16(const short* sa, int sstride,
                                             short* dst_,
                                             const short* __restrict__ wf,
                                             const float* __restrict__ bias,
                                             int dout, int w, int l) {
    int abase = (l & 15) * sstride + ((l >> 4) * 8);
    int c_lane = l & 15;
    for (int ct = w; ct < CT; ct += 4) {
        f32x4 acc = {0.f, 0.f, 0.f, 0.f};
        const f16x8* wp = (const f16x8*)wf + (size_t)(ct * KS) * 64 + l;
#pragma unroll
        for (int ks = 0; ks < KS; ++ks) {
            f16x8 av = *(const f16x8*)(sa + abase + ks * 32);
            f16x8 wv = wp[ks * 64];
            acc = __builtin_amdgcn_mfma_f32_16x16x32_f16(av, wv, acc, 0, 0, 0);
        }
        int c = ct * 16 + c_lane;
        float bb = (c < dout) ? bias[c] : 0.f;
        int row0 = (l >> 4) * 4;
#pragma unroll
        for (int j = 0; j < 4; ++j) {
            float v = acc[j] + bb;
            v = v > 0.f ? v : 0.f;
            dst_[(row0 + j) * 200 + c] = f2h(v);
        }
    }
}

__global__ __launch_bounds__(256) void k_mlp(const __half* __restrict__ agg,
                                             const short* __restrict__ wf,
                                             const float* __restrict__ b1,
                                             const float* __restrict__ b2,
                                             const float* __restrict__ b3,
                                             const float* __restrict__ b4,
                                             const float* __restrict__ b5,
                                             const float* __restrict__ b6,
                                             const float* __restrict__ w7,
                                             const float* __restrict__ b7,
                                             const float* __restrict__ wt,
                                             float* __restrict__ outp) {
    __shared__ __align__(16) short smem[13600];
    __shared__ float wx[16];
    short* g  = smem;           // [16][648] fp16
    short* h0 = smem + 10368;   // [16][200]
    short* h1 = smem;           // overlays g (dead after L1)

    int tid = threadIdx.x;
    int w = tid >> 6, l = tid & 63;
    int p0 = blockIdx.x * 16;

    const s16x8* a8 = (const s16x8*)(agg + (size_t)p0 * 640);
    for (int i = tid; i < 16 * 80; i += 256) {
        int r = i / 80, c8 = (i % 80) * 8;
        *(s16x8*)(g + r * 648 + c8) = a8[i];
    }

    if (tid < 128) {
        int path = tid >> 3, sub = tid & 7;
        const __half* gr = agg + (size_t)(p0 + path) * 640;
        float acc = 0.f;
        for (int k = sub * 4; k < 640; k += 32) {
            s16x4 gv = *(const s16x4*)(gr + k);
            float4 wv = *(const float4*)(wt + k);
            acc += h2f(gv[0]) * wv.x + h2f(gv[1]) * wv.y
                 + h2f(gv[2]) * wv.z + h2f(gv[3]) * wv.w;
        }
        acc += __shfl_xor(acc, 1);
        acc += __shfl_xor(acc, 2);
        acc += __shfl_xor(acc, 4);
        if (sub == 0) wx[path] = acc;
    }
    __syncthreads();

    mfma_layer16<20, 12>(g, 648, h0, wf + 0,      b1, 180, w, l);
    __syncthreads();
    mfma_layer16<6, 10>(h0, 200, h1, wf + 122880, b2, 150, w, l);
    __syncthreads();
    mfma_layer16<5, 8>(h1, 200, h0, wf + 153600, b3, 128, w, l);
    __syncthreads();
    mfma_layer16<4, 5>(h0, 200, h1, wf + 174080, b4, 80, w, l);
    {
        int r = tid >> 4, c = 80 + (tid & 15);
        h1[r * 200 + c] = 0;
    }
    __syncthreads();
    mfma_layer16<3, 4>(h1, 200, h0, wf + 184320, b5, 64, w, l);
    __syncthreads();
    mfma_layer16<2, 2>(h0, 200, h1, wf + 190464, b6, 32, w, l);
    __syncthreads();

    if (tid < 16) {
        float acc = b7[0];
#pragma unroll
        for (int k = 0; k < 32; ++k)
            acc += h2f(h1[tid * 200 + k]) * w7[k];
        outp[p0 + tid] = acc + wx[tid];
    }
}

extern "C" void kernel_launch(void* const* d_in, const int* in_sizes, int n_in,
                              void* d_out, int out_size, void* d_ws, size_t ws_size,
                              hipStream_t stream) {
    const float* x      = (const float*)d_in[0];
    const int*   src    = (const int*)d_in[1];
    const int*   dst    = (const int*)d_in[2];
    const float* fc_w   = (const float*)d_in[3];
    const float* bias   = (const float*)d_in[4];
    const float* attn_l = (const float*)d_in[5];
    const float* attn_r = (const float*)d_in[6];
    const float* w1 = (const float*)d_in[7];  const float* b1 = (const float*)d_in[8];
    const float* w2 = (const float*)d_in[9];  const float* b2 = (const float*)d_in[10];
    const float* w3 = (const float*)d_in[11]; const float* b3 = (const float*)d_in[12];
    const float* w4 = (const float*)d_in[13]; const float* b4 = (const float*)d_in[14];
    const float* w5 = (const float*)d_in[15]; const float* b5 = (const float*)d_in[16];
    const float* w6 = (const float*)d_in[17]; const float* b6 = (const float*)d_in[18];
    const float* w7 = (const float*)d_in[19]; const float* b7 = (const float*)d_in[20];
    const float* wt = (const float*)d_in[21];
    int E = in_sizes[1];

    float* ws      = (float*)d_ws;
    __half* feat   = (__half*)ws;               // 6.4M fp16
    float* el      = ws + 6400000;              //   400,000 f
    float* er      = ws + 6800000;              //   400,000 f
    __half* agg    = (__half*)(ws + 7200000);   // 6.4M fp16
    unsigned* pair = (unsigned*)(ws + 10400000);// E u32
    int*   rowptr  = (int*)(ws + 13600000);     //   100,001 i (pad 100,004)
    int*   buktot  = (int*)(ws + 13700004);     //       391 i
    int*   bukstart= (int*)(ws + 13700400);     //       392 i
    int*   bukptr  = (int*)(ws + 13700800);     //       391 i
    int*   csr     = (int*)(ws + 13701200);     //         E i
    short* wf      = (short*)(ws + 13701200 + E); // 192,512 fp16

    int nwgA = (E + 2047) / 2048;

    hipMemsetAsync(buktot, 0, NBUK * 4, stream);

    k_fused1<<<FEAT_BLKS + HIST_BLKS + WPREP_BLKS, 256, 0, stream>>>(
        x, fc_w, attn_l, attn_r, feat, el, er, dst, buktot,
        w1, w2, w3, w4, w5, w6, wf, E);
    k_scanB<<<1, 512, 0, stream>>>(buktot, bukstart, bukptr, rowptr, E);
    k_bucketA<<<nwgA, 256, 0, stream>>>(src, dst, bukptr, pair, E);
    k_bucketC<<<NBUK, 256, 0, stream>>>(pair, bukstart, rowptr, csr, E);
    k_agg<<<N_NODES / 4, 256, 0, stream>>>(rowptr, csr, el, er, feat, bias, agg);
    k_mlp<<<P_PATHS / 16, 256, 0, stream>>>(agg, wf, b1, b2, b3, b4, b5, b6,
                                            w7, b7, wt, (float*)d_out);
}